// Round 6
// baseline (10890.755 us; speedup 1.0000x reference)
//
#include <hip/hip_runtime.h>
#include <hip/hip_bf16.h>

// ---------------------------------------------------------------------------
// UnifiedModelRNN: B=256,S=512,I=64,H=256. 16 blocks x 576 threads (9 waves),
// 1 block/CU; block g owns batch rows [16g,16g+16). No grid sync.
// R6: wave specialization. Waves 0-7: gates GEMM + LSTM (each owns 32 hidden
// units). Wave 8: ENTIRE head chain (pit->time->ar1->ar2) for all 16 rows,
// in-wave reductions. 2 lgkmcnt-only barriers/step:
//   [x(t) ready] gates-x + LSTM -> h  |barrier A|
//   waves0-7: gates-h(t+1) streamed   |  wave 8: head chain -> x(t+1)
//   |barrier B| -> next step.
// Gate weights: kt9 LDS-resident, kt0-8 streamed (frag-major, coalesced)
// through 2 rotating 8-frag buffers in the unbroken region.
// Head weights: pit_w1/time_w1 LDS-resident; ar weights streamed (tiny).
// ---------------------------------------------------------------------------

typedef float f32x4 __attribute__((ext_vector_type(4)));
typedef short s16x8 __attribute__((ext_vector_type(8)));

#define S_LEN 512
#define I_DIM 64
#define K_DIM 320
#define NT    576

#define WS_GF    0
#define WS_PF    327680
#define WS_TF    344064
#define WS_AXF   360448
#define WS_A2F   364544
#define WS_TOTAL 368640

#define OUT_PIT  0
#define OUT_TIME 131072
#define OUT_AR   262144

#define ALD 328
#define XLD 72

__device__ __forceinline__ float sigf(float x) {
  return 1.0f / (1.0f + __expf(-x));
}
__device__ __forceinline__ float tanh_fast(float x) {
  float c = fminf(fmaxf(x, -15.0f), 15.0f);
  float e = __expf(2.0f * c);
  return (e - 1.0f) / (e + 1.0f);
}
__device__ __forceinline__ unsigned short f2bf(float f) {
  __hip_bfloat16 h = __float2bfloat16(f);
  return *reinterpret_cast<unsigned short*>(&h);
}
// LDS-only barrier: does NOT drain vmcnt -> global loads stay in flight.
__device__ __forceinline__ void sync_lds() {
  asm volatile("s_waitcnt lgkmcnt(0)" ::: "memory");
  __builtin_amdgcn_s_barrier();
  asm volatile("" ::: "memory");
}

__global__ void prep_kernel(const float* __restrict__ w_ih,
                            const float* __restrict__ w_hh,
                            const float* __restrict__ pit_w1,
                            const float* __restrict__ time_w1,
                            const float* __restrict__ ar_w1,
                            const float* __restrict__ ar_w2,
                            unsigned short* __restrict__ ws) {
  int idx = blockIdx.x * 256 + threadIdx.x;
  if (idx >= WS_TOTAL) return;
  int lane = (idx >> 3) & 63;
  int e    = idx & 7;
  int lrow = lane & 15, lgrp = lane >> 4;
  float v;
  if (idx < WS_PF) {
    int f = idx >> 9;
    int w = f / 80, r = f - w * 80;
    int qm = r / 10, kt = r - qm * 10;
    int q = qm >> 1, m = qm & 1;
    int row = q * 256 + w * 32 + m * 16 + lrow;
    int col = kt * 32 + lgrp * 8 + e;
    v = (col < I_DIM) ? w_ih[row * I_DIM + col] : w_hh[row * 256 + col - I_DIM];
  } else if (idx < WS_TF) {
    int f = (idx - WS_PF) >> 9;
    int wv = f >> 3, kt = f & 7;
    v = pit_w1[(wv * 16 + lrow) * 256 + kt * 32 + lgrp * 8 + e];
  } else if (idx < WS_AXF) {
    int f = (idx - WS_TF) >> 9;
    int wv = f >> 3, kt = f & 7;
    v = time_w1[(wv * 16 + lrow) * 257 + kt * 32 + lgrp * 8 + e];
  } else if (idx < WS_A2F) {
    int f = (idx - WS_AXF) >> 9;
    int wv = f >> 1, kt = f & 1;
    v = ar_w1[(wv * 16 + lrow) * 66 + 2 + kt * 32 + lgrp * 8 + e];
  } else {
    int f = (idx - WS_A2F) >> 9;
    int wv = f >> 1, kt = f & 1;
    v = ar_w2[(wv * 16 + lrow) * 64 + kt * 32 + lgrp * 8 + e];
  }
  ws[idx] = f2bf(v);
}

#define AFRAG(kt) (*(const s16x8*)&A_lds[lrow][(kt) * 32 + 8 * lgrp])
#define GFRAG(kt, qm) (*(const s16x8*)&ws[((wave * 80 + (qm) * 10 + (kt)) * 64 + lane) * 8])
#define PFRAG(ct, kt) (*(const s16x8*)&pit_lds[(((ct) * 8 + (kt)) * 64 + lane) * 8])
#define TFRAG(ct, kt) (*(const s16x8*)&tim_lds[(((ct) * 8 + (kt)) * 64 + lane) * 8])
#define ARXF(ct, kt) (*(const s16x8*)&ws[WS_AXF + (((ct) * 2 + (kt)) * 64 + lane) * 8])
#define AW2F(ct, kt) (*(const s16x8*)&ws[WS_A2F + (((ct) * 2 + (kt)) * 64 + lane) * 8])
#define GB(af, buf)                                                              \
  _Pragma("unroll") for (int qm = 0; qm < 8; ++qm)                               \
      acc2[qm] = __builtin_amdgcn_mfma_f32_16x16x32_bf16((af), (buf)[qm],        \
                                                         acc2[qm], 0, 0, 0);
#define LOADB(buf, kt)                                                           \
  _Pragma("unroll") for (int qm = 0; qm < 8; ++qm) (buf)[qm] = GFRAG(kt, qm);

__global__ __launch_bounds__(NT) void rnn_kernel(
    const float* __restrict__ x,
    const float* __restrict__ b_ih, const float* __restrict__ b_hh,
    const float* __restrict__ pit_b1, const float* __restrict__ pit_w2,
    const float* __restrict__ pit_b2,
    const float* __restrict__ time_w1, const float* __restrict__ time_b1,
    const float* __restrict__ time_w2, const float* __restrict__ time_b2,
    const float* __restrict__ ar_w1, const float* __restrict__ ar_b1,
    const float* __restrict__ ar_b2,
    const unsigned short* __restrict__ ws,
    float* __restrict__ out)
{
  __shared__ __align__(16) unsigned short A_lds[16][ALD];    // [x(64) | h(256)]
  __shared__ __align__(16) unsigned short xo_lds[16][XLD];   // x_orig[t]
  __shared__ __align__(16) unsigned short ar1_lds[16][XLD];  // relu(ar1), wave-8 private
  __shared__ __align__(16) unsigned short g9_lds[64 * 512];  // gate kt9 frags (64 KB)
  __shared__ __align__(16) unsigned short pit_lds[32 * 512]; // pit_w1 frags (32 KB)
  __shared__ __align__(16) unsigned short tim_lds[32 * 512]; // time_w1 frags (32 KB)

  const int tid  = threadIdx.x;
  const int wave = tid >> 6;     // 0..8
  const int lane = tid & 63;
  const int lrow = lane & 15;
  const int lgrp = lane >> 4;
  const int b0   = blockIdx.x * 16;

  // ---- one-time LDS weight staging ----
  for (int c = tid; c < 4096; c += NT) {
    int f = c >> 6, lc = c & 63;
    int fws = (f >> 3) * 80 + (f & 7) * 10 + 9;
    *(s16x8*)&g9_lds[c * 8] = *(const s16x8*)&ws[(fws * 64 + lc) * 8];
  }
  for (int c = tid; c < 2048; c += NT) {
    *(s16x8*)&pit_lds[c * 8] = *(const s16x8*)&ws[WS_PF + c * 8];
    *(s16x8*)&tim_lds[c * 8] = *(const s16x8*)&ws[WS_TF + c * 8];
  }
  for (int i = tid; i < 16 * ALD; i += NT) (&A_lds[0][0])[i] = 0;

  // ---- role constants ----
  float gbias[8];
  if (wave < 8) {
#pragma unroll
    for (int qm = 0; qm < 8; ++qm) {
      int g = (qm >> 1) * 256 + wave * 32 + (qm & 1) * 16 + lrow;
      gbias[qm] = b_ih[g] + b_hh[g];
    }
  }
  float pb1v[4], pw2v[4], tb1v[4], tw2v[4], twlv[4];
  float ab1v[4], arpv[4], artv[4], ab2v[4];
  if (wave == 8) {
#pragma unroll
    for (int ct = 0; ct < 4; ++ct) {
      int hc = ct * 16 + lrow;
      pb1v[ct] = pit_b1[hc];  pw2v[ct] = pit_w2[hc];
      tb1v[ct] = time_b1[hc]; tw2v[ct] = time_w2[hc];
      twlv[ct] = time_w1[hc * 257 + 256];
      ab1v[ct] = ar_b1[hc];   ab2v[ct] = ar_b2[hc];
      arpv[ct] = ar_w1[hc * 66]; artv[ct] = ar_w1[hc * 66 + 1];
    }
  }
  const float pb2 = pit_b2[0], tb2 = time_b2[0];

  // ---- stage x[:,0,:], write ar_out[:,0,:] (threads 0..511) ----
  const int srow = tid >> 5;
  const int sc2  = (tid & 31) * 2;
  const size_t xbase = (size_t)(b0 + (srow & 15)) * S_LEN * I_DIM + sc2;
  float2 xpre = {0.0f, 0.0f};
  if (tid < 512) xpre = *reinterpret_cast<const float2*>(&x[xbase]);
  __syncthreads();
  if (tid < 512) {
    A_lds[srow][sc2]     = f2bf(xpre.x);
    A_lds[srow][sc2 + 1] = f2bf(xpre.y);
    *reinterpret_cast<float2*>(&out[OUT_AR + xbase]) = xpre;
  }

  float cst[2][4];
#pragma unroll
  for (int m = 0; m < 2; ++m)
#pragma unroll
    for (int r = 0; r < 4; ++r) cst[m][r] = 0.0f;

  // gates(0): h=0 so h-part contributes nothing -> acc2 = bias only.
  f32x4 acc2[8];
  s16x8 bldA[8], bldB[8];
  if (wave < 8) {
#pragma unroll
    for (int qm = 0; qm < 8; ++qm) {
      f32x4 tv; tv[0] = tv[1] = tv[2] = tv[3] = gbias[qm];
      acc2[qm] = tv;
    }
    LOADB(bldB, 0);
    LOADB(bldA, 1);
  }
  __syncthreads();

  // =========================== time loop ===========================
  for (int t = 0; t < S_LEN; ++t) {
    if (wave < 8) {
      // ---- gates-x: kt0 (bldB), kt1 (bldA); refill with kt2,kt3 ----
      {
        s16x8 a0 = AFRAG(0);
        GB(a0, bldB);
      }
      LOADB(bldB, 2);
      {
        s16x8 a1 = AFRAG(1);
        GB(a1, bldA);
      }
      LOADB(bldA, 3);

      // stage x_orig[t]; prefetch x[t+1]
      if (tid < 512) {
        xo_lds[srow][sc2]     = f2bf(xpre.x);
        xo_lds[srow][sc2 + 1] = f2bf(xpre.y);
        if (t + 1 < S_LEN)
          xpre = *reinterpret_cast<const float2*>(&x[xbase + (size_t)(t + 1) * I_DIM]);
      }

      // ---- LSTM (c in regs) -> h into A_lds; reset acc ----
#pragma unroll
      for (int m = 0; m < 2; ++m)
#pragma unroll
        for (int r = 0; r < 4; ++r) {
          float ig = sigf(acc2[0 + m][r]);
          float fg = sigf(acc2[2 + m][r]);
          float gg = tanh_fast(acc2[4 + m][r]);
          float og = sigf(acc2[6 + m][r]);
          float c  = fg * cst[m][r] + ig * gg;
          cst[m][r] = c;
          A_lds[lgrp * 4 + r][64 + wave * 32 + m * 16 + lrow] = f2bf(og * tanh_fast(c));
        }
#pragma unroll
      for (int qm = 0; qm < 8; ++qm) {
        f32x4 tv; tv[0] = tv[1] = tv[2] = tv[3] = gbias[qm];
        acc2[qm] = tv;
      }
    }
    sync_lds();  // barrier A: h(t) + xo(t) ready

    if (wave < 8) {
      // ---- gates-h for t+1: kt2..kt8 streamed, kt9 from LDS ----
      { s16x8 a = AFRAG(2); GB(a, bldB); } LOADB(bldB, 4);
      { s16x8 a = AFRAG(3); GB(a, bldA); } LOADB(bldA, 5);
      { s16x8 a = AFRAG(4); GB(a, bldB); } LOADB(bldB, 6);
      { s16x8 a = AFRAG(5); GB(a, bldA); } LOADB(bldA, 7);
      { s16x8 a = AFRAG(6); GB(a, bldB); } LOADB(bldB, 8);
      { s16x8 a = AFRAG(7); GB(a, bldA); } LOADB(bldA, 1);  // next iter kt1
      { s16x8 a = AFRAG(8); GB(a, bldB); } LOADB(bldB, 0);  // next iter kt0
      {
        s16x8 a9 = AFRAG(9);
#pragma unroll
        for (int qm = 0; qm < 8; ++qm) {
          s16x8 bK = *(const s16x8*)&g9_lds[((wave * 8 + qm) * 64 + lane) * 8];
          acc2[qm] = __builtin_amdgcn_mfma_f32_16x16x32_bf16(a9, bK, acc2[qm], 0, 0, 0);
        }
      }
    } else {
      // ================= wave 8: full head chain =================
      s16x8 hfr[8];
#pragma unroll
      for (int kt = 0; kt < 8; ++kt)
        hfr[kt] = *(const s16x8*)&A_lds[lrow][64 + kt * 32 + 8 * lgrp];

      // pit1 = relu(h @ pit_w1^T + b1); pit = pit1 @ pit_w2^T + b2
      f32x4 pacc[4];
#pragma unroll
      for (int ct = 0; ct < 4; ++ct) {
        f32x4 tv; tv[0] = tv[1] = tv[2] = tv[3] = pb1v[ct];
        pacc[ct] = tv;
      }
#pragma unroll
      for (int kt = 0; kt < 8; ++kt)
#pragma unroll
        for (int ct = 0; ct < 4; ++ct)
          pacc[ct] = __builtin_amdgcn_mfma_f32_16x16x32_bf16(hfr[kt], PFRAG(ct, kt), pacc[ct], 0, 0, 0);
      float pv[4];
#pragma unroll
      for (int r = 0; r < 4; ++r)
        pv[r] = fmaxf(pacc[0][r], 0.0f) * pw2v[0] + fmaxf(pacc[1][r], 0.0f) * pw2v[1] +
                fmaxf(pacc[2][r], 0.0f) * pw2v[2] + fmaxf(pacc[3][r], 0.0f) * pw2v[3];
#pragma unroll
      for (int off = 1; off < 16; off <<= 1)
#pragma unroll
        for (int r = 0; r < 4; ++r) pv[r] += __shfl_xor(pv[r], off);
#pragma unroll
      for (int r = 0; r < 4; ++r) pv[r] += pb2;

      // time1 = relu(h @ tw1[:, :256]^T + pit*tw1[:,256] + b1); time = @tw2 + b2
      f32x4 tacc[4];
#pragma unroll
      for (int ct = 0; ct < 4; ++ct) {
        f32x4 tv; tv[0] = tv[1] = tv[2] = tv[3] = tb1v[ct];
        tacc[ct] = tv;
      }
#pragma unroll
      for (int kt = 0; kt < 8; ++kt)
#pragma unroll
        for (int ct = 0; ct < 4; ++ct)
          tacc[ct] = __builtin_amdgcn_mfma_f32_16x16x32_bf16(hfr[kt], TFRAG(ct, kt), tacc[ct], 0, 0, 0);
      float tv[4];
#pragma unroll
      for (int r = 0; r < 4; ++r)
        tv[r] = fmaxf(tacc[0][r] + pv[r] * twlv[0], 0.0f) * tw2v[0] +
                fmaxf(tacc[1][r] + pv[r] * twlv[1], 0.0f) * tw2v[1] +
                fmaxf(tacc[2][r] + pv[r] * twlv[2], 0.0f) * tw2v[2] +
                fmaxf(tacc[3][r] + pv[r] * twlv[3], 0.0f) * tw2v[3];
#pragma unroll
      for (int off = 1; off < 16; off <<= 1)
#pragma unroll
        for (int r = 0; r < 4; ++r) tv[r] += __shfl_xor(tv[r], off);
#pragma unroll
      for (int r = 0; r < 4; ++r) tv[r] += tb2;

      if (lrow == 0) {
#pragma unroll
        for (int r = 0; r < 4; ++r) {
          out[OUT_PIT  + (size_t)(b0 + lgrp * 4 + r) * S_LEN + t] = pv[r];
          out[OUT_TIME + (size_t)(b0 + lgrp * 4 + r) * S_LEN + t] = tv[r];
        }
      }

      // ar1 = relu([pit,time,x_orig] @ ar_w1^T + b1)
      s16x8 xf0 = *(const s16x8*)&xo_lds[lrow][8 * lgrp];
      s16x8 xf1 = *(const s16x8*)&xo_lds[lrow][32 + 8 * lgrp];
      f32x4 aacc[4];
#pragma unroll
      for (int ct = 0; ct < 4; ++ct) {
        f32x4 t0; t0[0] = t0[1] = t0[2] = t0[3] = ab1v[ct];
        aacc[ct] = __builtin_amdgcn_mfma_f32_16x16x32_bf16(xf0, ARXF(ct, 0), t0, 0, 0, 0);
        aacc[ct] = __builtin_amdgcn_mfma_f32_16x16x32_bf16(xf1, ARXF(ct, 1), aacc[ct], 0, 0, 0);
      }
#pragma unroll
      for (int ct = 0; ct < 4; ++ct)
#pragma unroll
        for (int r = 0; r < 4; ++r) {
          float a1 = aacc[ct][r] + pv[r] * arpv[ct] + tv[r] * artv[ct];
          ar1_lds[lgrp * 4 + r][ct * 16 + lrow] = f2bf(fmaxf(a1, 0.0f));
        }
      // ar2 -> x_{t+1} (compiler inserts lgkm wait for the write->read dep)
      s16x8 af0 = *(const s16x8*)&ar1_lds[lrow][8 * lgrp];
      s16x8 af1 = *(const s16x8*)&ar1_lds[lrow][32 + 8 * lgrp];
      f32x4 nacc[4];
#pragma unroll
      for (int ct = 0; ct < 4; ++ct) {
        f32x4 t0; t0[0] = t0[1] = t0[2] = t0[3] = ab2v[ct];
        nacc[ct] = __builtin_amdgcn_mfma_f32_16x16x32_bf16(af0, AW2F(ct, 0), t0, 0, 0, 0);
        nacc[ct] = __builtin_amdgcn_mfma_f32_16x16x32_bf16(af1, AW2F(ct, 1), nacc[ct], 0, 0, 0);
      }
#pragma unroll
      for (int ct = 0; ct < 4; ++ct)
#pragma unroll
        for (int r = 0; r < 4; ++r) {
          int row = lgrp * 4 + r;
          A_lds[row][ct * 16 + lrow] = f2bf(nacc[ct][r]);
          if (t < S_LEN - 1)
            out[OUT_AR + (size_t)(b0 + row) * S_LEN * I_DIM + (size_t)(t + 1) * I_DIM + ct * 16 + lrow] = nacc[ct][r];
        }
    }
    sync_lds();  // barrier B: x(t+1) staged
  }
}

extern "C" void kernel_launch(void* const* d_in, const int* in_sizes, int n_in,
                              void* d_out, int out_size, void* d_ws, size_t ws_size,
                              hipStream_t stream) {
  const float* x       = (const float*)d_in[0];
  const float* w_ih    = (const float*)d_in[1];
  const float* w_hh    = (const float*)d_in[2];
  const float* b_ih    = (const float*)d_in[3];
  const float* b_hh    = (const float*)d_in[4];
  const float* pit_w1  = (const float*)d_in[5];
  const float* pit_b1  = (const float*)d_in[6];
  const float* pit_w2  = (const float*)d_in[7];
  const float* pit_b2  = (const float*)d_in[8];
  const float* time_w1 = (const float*)d_in[9];
  const float* time_b1 = (const float*)d_in[10];
  const float* time_w2 = (const float*)d_in[11];
  const float* time_b2 = (const float*)d_in[12];
  const float* ar_w1   = (const float*)d_in[13];
  const float* ar_b1   = (const float*)d_in[14];
  const float* ar_w2   = (const float*)d_in[15];
  const float* ar_b2   = (const float*)d_in[16];
  unsigned short* ws   = (unsigned short*)d_ws;
  float* out           = (float*)d_out;

  prep_kernel<<<dim3((WS_TOTAL + 255) / 256), dim3(256), 0, stream>>>(
      w_ih, w_hh, pit_w1, time_w1, ar_w1, ar_w2, ws);
  rnn_kernel<<<dim3(16), dim3(NT), 0, stream>>>(
      x, b_ih, b_hh, pit_b1, pit_w2, pit_b2,
      time_w1, time_b1, time_w2, time_b2,
      ar_w1, ar_b1, ar_b2, ws, out);
}

// Round 7
// 8487.931 us; speedup vs baseline: 1.2831x; 1.2831x over previous
//
#include <hip/hip_runtime.h>
#include <hip/hip_bf16.h>

// ---------------------------------------------------------------------------
// UnifiedModelRNN: B=256,S=512,I=64,H=256. 16 blocks x 256 threads (4 waves,
// 1 wave/SIMD); block g owns batch rows [16g,16g+16). No grid sync.
// R7: __launch_bounds__(256,1) -> 512-VGPR budget (requirement ~320, so no
// spill/remat). Wave w owns hidden units [64w,64w+64) x 4 gates: acc2[16],
// LSTM thread-local. Gate kts{0..8} streamed (frag-major, coalesced) through
// TWO alternating 16-frag register buffers, each LD issued >=1 bundle before
// use and surviving lgkmcnt-only barriers; kt9 + pit/time weights LDS-
// resident. 5 barriers/step. Heads: waves 0-1 pit+ar1, waves 2-3 time+ar2.
// ---------------------------------------------------------------------------

typedef float f32x4 __attribute__((ext_vector_type(4)));
typedef short s16x8 __attribute__((ext_vector_type(8)));

#define S_LEN 512
#define I_DIM 64
#define NT    256

#define WS_GF    0        // gates: 640 frags x 512 elems, f=((w*16+qm)*10+kt)
#define WS_PF    327680   // pit_w1: 32 frags (ct*8+kt)
#define WS_TF    344064   // time_w1[:, :256]: 32 frags
#define WS_AXF   360448   // ar_w1[:, 2:66]: 8 frags (ct*2+kt)
#define WS_A2F   364544   // ar_w2: 8 frags
#define WS_TOTAL 368640

#define OUT_PIT  0
#define OUT_TIME 131072
#define OUT_AR   262144

#define ALD 328
#define XLD 72

__device__ __forceinline__ float sigf(float x) {
  return 1.0f / (1.0f + __expf(-x));
}
__device__ __forceinline__ float tanh_fast(float x) {
  float c = fminf(fmaxf(x, -15.0f), 15.0f);
  float e = __expf(2.0f * c);
  return (e - 1.0f) / (e + 1.0f);
}
__device__ __forceinline__ unsigned short f2bf(float f) {
  __hip_bfloat16 h = __float2bfloat16(f);
  return *reinterpret_cast<unsigned short*>(&h);
}
// LDS-only barrier: does NOT drain vmcnt -> global loads stay in flight.
__device__ __forceinline__ void sync_lds() {
  asm volatile("s_waitcnt lgkmcnt(0)" ::: "memory");
  __builtin_amdgcn_s_barrier();
  asm volatile("" ::: "memory");
}

__global__ void prep_kernel(const float* __restrict__ w_ih,
                            const float* __restrict__ w_hh,
                            const float* __restrict__ pit_w1,
                            const float* __restrict__ time_w1,
                            const float* __restrict__ ar_w1,
                            const float* __restrict__ ar_w2,
                            unsigned short* __restrict__ ws) {
  int idx = blockIdx.x * 256 + threadIdx.x;
  if (idx >= WS_TOTAL) return;
  int lane = (idx >> 3) & 63;
  int e    = idx & 7;
  int lrow = lane & 15, lgrp = lane >> 4;
  float v;
  if (idx < WS_PF) {
    int f = idx >> 9;                 // 0..639
    int w = f / 160, r = f - w * 160;
    int qm = r / 10, kt = r - qm * 10;
    int q = qm >> 2, m = qm & 3;
    int row = q * 256 + w * 64 + m * 16 + lrow;
    int col = kt * 32 + lgrp * 8 + e;
    v = (col < I_DIM) ? w_ih[row * I_DIM + col] : w_hh[row * 256 + col - I_DIM];
  } else if (idx < WS_TF) {
    int f = (idx - WS_PF) >> 9;       // ct*8+kt
    int ct = f >> 3, kt = f & 7;
    v = pit_w1[(ct * 16 + lrow) * 256 + kt * 32 + lgrp * 8 + e];
  } else if (idx < WS_AXF) {
    int f = (idx - WS_TF) >> 9;
    int ct = f >> 3, kt = f & 7;
    v = time_w1[(ct * 16 + lrow) * 257 + kt * 32 + lgrp * 8 + e];
  } else if (idx < WS_A2F) {
    int f = (idx - WS_AXF) >> 9;      // ct*2+kt
    int ct = f >> 1, kt = f & 1;
    v = ar_w1[(ct * 16 + lrow) * 66 + 2 + kt * 32 + lgrp * 8 + e];
  } else {
    int f = (idx - WS_A2F) >> 9;
    int ct = f >> 1, kt = f & 1;
    v = ar_w2[(ct * 16 + lrow) * 64 + kt * 32 + lgrp * 8 + e];
  }
  ws[idx] = f2bf(v);
}

#define AFRAG(kt) (*(const s16x8*)&A_lds[lrow][(kt) * 32 + 8 * lgrp])
#define GFRAG(kt, qm) \
  (*(const s16x8*)&ws[(((wave * 16 + (qm)) * 10 + (kt)) * 512) + lane * 8])
#define HFRAG(hlds, ct, k) (*(const s16x8*)&(hlds)[(((ct) * 8 + (k)) * 512) + lane * 8])
#define ARXF(ct, kt) (*(const s16x8*)&ws[WS_AXF + (((ct) * 2 + (kt)) * 512) + lane * 8])
#define AW2F(ct, kt) (*(const s16x8*)&ws[WS_A2F + (((ct) * 2 + (kt)) * 512) + lane * 8])
#define GB(af, buf)                                                              \
  _Pragma("unroll") for (int qm = 0; qm < 16; ++qm)                              \
      acc2[qm] = __builtin_amdgcn_mfma_f32_16x16x32_bf16((af), (buf)[qm],        \
                                                         acc2[qm], 0, 0, 0);
#define LD(buf, kt)                                                              \
  _Pragma("unroll") for (int qm = 0; qm < 16; ++qm) (buf)[qm] = GFRAG(kt, qm);

__global__ __launch_bounds__(NT, 1) void rnn_kernel(
    const float* __restrict__ x,
    const float* __restrict__ b_ih, const float* __restrict__ b_hh,
    const float* __restrict__ pit_b1, const float* __restrict__ pit_w2,
    const float* __restrict__ pit_b2,
    const float* __restrict__ time_w1, const float* __restrict__ time_b1,
    const float* __restrict__ time_w2, const float* __restrict__ time_b2,
    const float* __restrict__ ar_w1, const float* __restrict__ ar_b1,
    const float* __restrict__ ar_b2,
    const unsigned short* __restrict__ ws,
    float* __restrict__ out)
{
  __shared__ __align__(16) unsigned short A_lds[16][ALD];    // [x(64) | h(256)]
  __shared__ __align__(16) unsigned short xo_lds[16][XLD];   // x_orig[t]
  __shared__ __align__(16) unsigned short ar1_lds[16][XLD];  // relu(ar1)
  __shared__ __align__(16) unsigned short g9_lds[64 * 512];  // gate kt9 (64 KB)
  __shared__ __align__(16) unsigned short pit_lds[32 * 512]; // pit_w1 (32 KB)
  __shared__ __align__(16) unsigned short tim_lds[32 * 512]; // time_w1 (32 KB)
  __shared__ float pitp[2][16];
  __shared__ float timep[2][16];

  const int tid  = threadIdx.x;
  const int wave = tid >> 6;     // 0..3
  const int lane = tid & 63;
  const int lrow = lane & 15;
  const int lgrp = lane >> 4;
  const int b0   = blockIdx.x * 16;
  const int ctb  = (wave & 1) * 2;   // head col-tile pair base

  // ---- one-time LDS weight staging ----
  for (int c = tid; c < 4096; c += NT) {
    int f = c >> 6, lc = c & 63;
    *(s16x8*)&g9_lds[c * 8] = *(const s16x8*)&ws[(f * 10 + 9) * 512 + lc * 8];
  }
  for (int c = tid; c < 2048; c += NT) {
    *(s16x8*)&pit_lds[c * 8] = *(const s16x8*)&ws[WS_PF + c * 8];
    *(s16x8*)&tim_lds[c * 8] = *(const s16x8*)&ws[WS_TF + c * 8];
  }
  for (int i = tid; i < 16 * ALD; i += NT) (&A_lds[0][0])[i] = 0;

  // ---- role constants ----
  float gbias[16];
#pragma unroll
  for (int qm = 0; qm < 16; ++qm) {
    int g = (qm >> 2) * 256 + wave * 64 + (qm & 3) * 16 + lrow;
    gbias[qm] = b_ih[g] + b_hh[g];
  }
  float hb1[2], hw2[2], twl[2], ab1[2], arp[2], art[2], ab2[2];
#pragma unroll
  for (int c2 = 0; c2 < 2; ++c2) {
    int hc = (ctb + c2) * 16 + lrow;
    if (wave < 2) {
      hb1[c2] = pit_b1[hc]; hw2[c2] = pit_w2[hc];
      ab1[c2] = ar_b1[hc];  arp[c2] = ar_w1[hc * 66]; art[c2] = ar_w1[hc * 66 + 1];
      twl[c2] = 0.0f; ab2[c2] = 0.0f;
    } else {
      hb1[c2] = time_b1[hc]; hw2[c2] = time_w2[hc];
      twl[c2] = time_w1[hc * 257 + 256]; ab2[c2] = ar_b2[hc];
      ab1[c2] = 0.0f; arp[c2] = 0.0f; art[c2] = 0.0f;
    }
  }
  const float pb2 = pit_b2[0], tb2 = time_b2[0];

  // ---- stage x[:,0,:], write ar_out[:,0,:] ----
  const int srow = tid >> 4;          // 0..15
  const int sc4  = (tid & 15) * 4;    // 0..60
  const size_t xbase = (size_t)(b0 + srow) * S_LEN * I_DIM + sc4;
  float4 xpre = *reinterpret_cast<const float4*>(&x[xbase]);
  __syncthreads();
  A_lds[srow][sc4]     = f2bf(xpre.x);
  A_lds[srow][sc4 + 1] = f2bf(xpre.y);
  A_lds[srow][sc4 + 2] = f2bf(xpre.z);
  A_lds[srow][sc4 + 3] = f2bf(xpre.w);
  *reinterpret_cast<float4*>(&out[OUT_AR + xbase]) = xpre;

  float cst[4][4];
#pragma unroll
  for (int m = 0; m < 4; ++m)
#pragma unroll
    for (int r = 0; r < 4; ++r) cst[m][r] = 0.0f;

  f32x4 acc2[16];
#pragma unroll
  for (int qm = 0; qm < 16; ++qm) {
    f32x4 tv; tv[0] = tv[1] = tv[2] = tv[3] = gbias[qm];
    acc2[qm] = tv;
  }
  __syncthreads();

  // prologue: gates(0) = bias + x0-part (h=0)
  {
    s16x8 a0 = AFRAG(0);
#pragma unroll
    for (int qm = 0; qm < 16; ++qm)
      acc2[qm] = __builtin_amdgcn_mfma_f32_16x16x32_bf16(a0, GFRAG(0, qm), acc2[qm], 0, 0, 0);
    s16x8 a1 = AFRAG(1);
#pragma unroll
    for (int qm = 0; qm < 16; ++qm)
      acc2[qm] = __builtin_amdgcn_mfma_f32_16x16x32_bf16(a1, GFRAG(1, qm), acc2[qm], 0, 0, 0);
  }
  s16x8 bufA[16], bufB[16];
  LD(bufA, 2);
  LD(bufB, 3);

  // =========================== time loop ===========================
  for (int t = 0; t < S_LEN; ++t) {
    // ---- P0: xo stage, x prefetch, LSTM -> h ----
    xo_lds[srow][sc4]     = f2bf(xpre.x);
    xo_lds[srow][sc4 + 1] = f2bf(xpre.y);
    xo_lds[srow][sc4 + 2] = f2bf(xpre.z);
    xo_lds[srow][sc4 + 3] = f2bf(xpre.w);
    if (t + 1 < S_LEN)
      xpre = *reinterpret_cast<const float4*>(&x[xbase + (size_t)(t + 1) * I_DIM]);

#pragma unroll
    for (int m = 0; m < 4; ++m)
#pragma unroll
      for (int r = 0; r < 4; ++r) {
        float ig = sigf(acc2[0 + m][r]);
        float fg = sigf(acc2[4 + m][r]);
        float gg = tanh_fast(acc2[8 + m][r]);
        float og = sigf(acc2[12 + m][r]);
        float c  = fg * cst[m][r] + ig * gg;
        cst[m][r] = c;
        A_lds[lgrp * 4 + r][64 + wave * 64 + m * 16 + lrow] = f2bf(og * tanh_fast(c));
      }
#pragma unroll
    for (int qm = 0; qm < 16; ++qm) {
      f32x4 tv; tv[0] = tv[1] = tv[2] = tv[3] = gbias[qm];
      acc2[qm] = tv;
    }
    sync_lds();  // barrier A: h + xo ready

    // ---- P1: gates kt2..kt5; pit/time main; pit partials ----
    s16x8 hfr[8];
#pragma unroll
    for (int k = 0; k < 8; ++k)
      hfr[k] = *(const s16x8*)&A_lds[lrow][64 + k * 32 + 8 * lgrp];

    GB(hfr[0], bufA); LD(bufA, 4);   // kt2
    GB(hfr[1], bufB); LD(bufB, 5);   // kt3

    f32x4 hacc[2];
    {
      const unsigned short* hlds = (wave < 2) ? pit_lds : tim_lds;
#pragma unroll
      for (int c2 = 0; c2 < 2; ++c2) {
        f32x4 tv; tv[0] = tv[1] = tv[2] = tv[3] = hb1[c2];
        hacc[c2] = tv;
      }
#pragma unroll
      for (int k = 0; k < 8; ++k)
#pragma unroll
        for (int c2 = 0; c2 < 2; ++c2)
          hacc[c2] = __builtin_amdgcn_mfma_f32_16x16x32_bf16(
              hfr[k], HFRAG(hlds, ctb + c2, k), hacc[c2], 0, 0, 0);
    }
    GB(hfr[2], bufA); LD(bufA, 6);   // kt4
    GB(hfr[3], bufB); LD(bufB, 7);   // kt5

    if (wave < 2) {
      float v[4];
#pragma unroll
      for (int r = 0; r < 4; ++r)
        v[r] = fmaxf(hacc[0][r], 0.0f) * hw2[0] + fmaxf(hacc[1][r], 0.0f) * hw2[1];
#pragma unroll
      for (int off = 1; off < 16; off <<= 1)
#pragma unroll
        for (int r = 0; r < 4; ++r) v[r] += __shfl_xor(v[r], off);
      if (lrow == 0) {
#pragma unroll
        for (int r = 0; r < 4; ++r) pitp[wave][lgrp * 4 + r] = v[r];
      }
    }
    sync_lds();  // barrier 1: pit partials ready

    // ---- P2: gates kt6,kt7; pv; time finish / ar1-x; pit out ----
    float pv[4];
#pragma unroll
    for (int r = 0; r < 4; ++r) {
      int row = lgrp * 4 + r;
      pv[r] = pitp[0][row] + pitp[1][row] + pb2;
    }
    GB(hfr[4], bufA); LD(bufA, 8);   // kt6

    f32x4 aacc[2];
    if (wave < 2) {
      s16x8 xf0 = *(const s16x8*)&xo_lds[lrow][8 * lgrp];
      s16x8 xf1 = *(const s16x8*)&xo_lds[lrow][32 + 8 * lgrp];
#pragma unroll
      for (int c2 = 0; c2 < 2; ++c2) {
        f32x4 t0; t0[0] = t0[1] = t0[2] = t0[3] = ab1[c2];
        aacc[c2] = __builtin_amdgcn_mfma_f32_16x16x32_bf16(xf0, ARXF(ctb + c2, 0), t0, 0, 0, 0);
        aacc[c2] = __builtin_amdgcn_mfma_f32_16x16x32_bf16(xf1, ARXF(ctb + c2, 1), aacc[c2], 0, 0, 0);
      }
      if (wave == 0 && lane < 16) {
        float pvs = pitp[0][lane] + pitp[1][lane] + pb2;
        out[OUT_PIT + (size_t)(b0 + lane) * S_LEN + t] = pvs;
      }
    } else {
      float v[4];
#pragma unroll
      for (int r = 0; r < 4; ++r)
        v[r] = fmaxf(hacc[0][r] + pv[r] * twl[0], 0.0f) * hw2[0] +
               fmaxf(hacc[1][r] + pv[r] * twl[1], 0.0f) * hw2[1];
#pragma unroll
      for (int off = 1; off < 16; off <<= 1)
#pragma unroll
        for (int r = 0; r < 4; ++r) v[r] += __shfl_xor(v[r], off);
      if (lrow == 0) {
#pragma unroll
        for (int r = 0; r < 4; ++r) timep[wave - 2][lgrp * 4 + r] = v[r];
      }
    }
    GB(hfr[5], bufB); LD(bufB, 0);   // kt7
    sync_lds();  // barrier 2: time partials ready

    // ---- P3: gates kt8; tv; ar1 finish; time out ----
    GB(hfr[6], bufA); LD(bufA, 1);   // kt8
    float tv[4];
#pragma unroll
    for (int r = 0; r < 4; ++r) {
      int row = lgrp * 4 + r;
      tv[r] = timep[0][row] + timep[1][row] + tb2;
    }
    if (wave < 2) {
#pragma unroll
      for (int c2 = 0; c2 < 2; ++c2)
#pragma unroll
        for (int r = 0; r < 4; ++r) {
          float a1 = aacc[c2][r] + pv[r] * arp[c2] + tv[r] * art[c2];
          ar1_lds[lgrp * 4 + r][(ctb + c2) * 16 + lrow] = f2bf(fmaxf(a1, 0.0f));
        }
    } else if (wave == 2 && lane < 16) {
      float tvs = timep[0][lane] + timep[1][lane] + tb2;
      out[OUT_TIME + (size_t)(b0 + lane) * S_LEN + t] = tvs;
    }
    sync_lds();  // barrier 3: ar1 ready

    // ---- P4: gates kt9 (LDS); ar2 -> x_{t+1} (waves 2-3) ----
    {
#pragma unroll
      for (int qm = 0; qm < 16; ++qm) {
        s16x8 bK = *(const s16x8*)&g9_lds[(wave * 16 + qm) * 512 + lane * 8];
        acc2[qm] = __builtin_amdgcn_mfma_f32_16x16x32_bf16(hfr[7], bK, acc2[qm], 0, 0, 0);
      }
    }
    if (wave >= 2) {
      s16x8 af0 = *(const s16x8*)&ar1_lds[lrow][8 * lgrp];
      s16x8 af1 = *(const s16x8*)&ar1_lds[lrow][32 + 8 * lgrp];
      f32x4 nacc[2];
#pragma unroll
      for (int c2 = 0; c2 < 2; ++c2) {
        f32x4 t0; t0[0] = t0[1] = t0[2] = t0[3] = ab2[c2];
        nacc[c2] = __builtin_amdgcn_mfma_f32_16x16x32_bf16(af0, AW2F(ctb + c2, 0), t0, 0, 0, 0);
        nacc[c2] = __builtin_amdgcn_mfma_f32_16x16x32_bf16(af1, AW2F(ctb + c2, 1), nacc[c2], 0, 0, 0);
      }
#pragma unroll
      for (int c2 = 0; c2 < 2; ++c2)
#pragma unroll
        for (int r = 0; r < 4; ++r) {
          int row = lgrp * 4 + r;
          int col = (ctb + c2) * 16 + lrow;
          A_lds[row][col] = f2bf(nacc[c2][r]);
          if (t < S_LEN - 1)
            out[OUT_AR + (size_t)(b0 + row) * S_LEN * I_DIM + (size_t)(t + 1) * I_DIM + col] = nacc[c2][r];
        }
    }
    sync_lds();  // barrier B: x_{t+1} staged

    // ---- P5: gates-x kt0 (bufB), kt1 (bufA); prime kt2,kt3 ----
    {
      s16x8 a0 = AFRAG(0);
      GB(a0, bufB);                  // kt0
      s16x8 a1 = AFRAG(1);
      GB(a1, bufA);                  // kt1
    }
    LD(bufA, 2);
    LD(bufB, 3);
  }
}

extern "C" void kernel_launch(void* const* d_in, const int* in_sizes, int n_in,
                              void* d_out, int out_size, void* d_ws, size_t ws_size,
                              hipStream_t stream) {
  const float* x       = (const float*)d_in[0];
  const float* w_ih    = (const float*)d_in[1];
  const float* w_hh    = (const float*)d_in[2];
  const float* b_ih    = (const float*)d_in[3];
  const float* b_hh    = (const float*)d_in[4];
  const float* pit_w1  = (const float*)d_in[5];
  const float* pit_b1  = (const float*)d_in[6];
  const float* pit_w2  = (const float*)d_in[7];
  const float* pit_b2  = (const float*)d_in[8];
  const float* time_w1 = (const float*)d_in[9];
  const float* time_b1 = (const float*)d_in[10];
  const float* time_w2 = (const float*)d_in[11];
  const float* time_b2 = (const float*)d_in[12];
  const float* ar_w1   = (const float*)d_in[13];
  const float* ar_b1   = (const float*)d_in[14];
  const float* ar_w2   = (const float*)d_in[15];
  const float* ar_b2   = (const float*)d_in[16];
  unsigned short* ws   = (unsigned short*)d_ws;
  float* out           = (float*)d_out;

  prep_kernel<<<dim3((WS_TOTAL + 255) / 256), dim3(256), 0, stream>>>(
      w_ih, w_hh, pit_w1, time_w1, ar_w1, ar_w2, ws);
  rnn_kernel<<<dim3(16), dim3(NT), 0, stream>>>(
      x, b_ih, b_hh, pit_b1, pit_w2, pit_b2,
      time_w1, time_b1, time_w2, time_b2,
      ar_w1, ar_b1, ar_b2, ws, out);
}

// Round 8
// 6384.631 us; speedup vs baseline: 1.7058x; 1.3294x over previous
//
#include <hip/hip_runtime.h>
#include <hip/hip_bf16.h>

// ---------------------------------------------------------------------------
// UnifiedModelRNN: B=256,S=512,I=64,H=256. 16 blocks x 512 threads (8 waves,
// 2/SIMD); block g owns batch rows [16g,16g+16). No grid sync.
// R8: gate weights streamed via global_load_lds DMA (no VGPR round-trip)
// into a per-wave-private 2-slot LDS ring (4KB chunks = 4 frags). Counted
// s_waitcnt vmcnt(4) per chunk (never 0); lgkm-only barriers so DMA rides
// across phases. Head chain schedule identical to R4 (passed). pit/time
// weights LDS-resident; ar weights register-resident.
// ---------------------------------------------------------------------------

typedef float f32x4 __attribute__((ext_vector_type(4)));
typedef short s16x8 __attribute__((ext_vector_type(8)));

#define S_LEN 512
#define I_DIM 64
#define NT    512

#define WS_GF    0        // gates: 640 frags x 512 elems, f = (wave*8+qm)*10+kt
#define WS_PF    327680   // pit_w1: 32 frags
#define WS_TF    344064   // time_w1[:, :256]: 32 frags
#define WS_AXF   360448   // ar_w1[:, 2:66]: 8 frags
#define WS_A2F   364544   // ar_w2: 8 frags
#define WS_TOTAL 368640

#define OUT_PIT  0
#define OUT_TIME 131072
#define OUT_AR   262144

#define ALD 328
#define XLD 72

__device__ __forceinline__ float sigf(float x) {
  return 1.0f / (1.0f + __expf(-x));
}
__device__ __forceinline__ float tanh_fast(float x) {
  float c = fminf(fmaxf(x, -15.0f), 15.0f);
  float e = __expf(2.0f * c);
  return (e - 1.0f) / (e + 1.0f);
}
__device__ __forceinline__ unsigned short f2bf(float f) {
  __hip_bfloat16 h = __float2bfloat16(f);
  return *reinterpret_cast<unsigned short*>(&h);
}
// LDS-only barrier: does NOT drain vmcnt -> DMA stays in flight.
__device__ __forceinline__ void sync_lds() {
  asm volatile("s_waitcnt lgkmcnt(0)" ::: "memory");
  __builtin_amdgcn_s_barrier();
  asm volatile("" ::: "memory");
}
// 16B/lane global->LDS DMA. gsrc per-lane; ldst wave-uniform base (+lane*16).
__device__ __forceinline__ void gld16(const unsigned short* g, unsigned short* l) {
  __builtin_amdgcn_global_load_lds(
      (const __attribute__((address_space(1))) unsigned int*)g,
      (__attribute__((address_space(3))) unsigned int*)l, 16, 0, 0);
}

__global__ void prep_kernel(const float* __restrict__ w_ih,
                            const float* __restrict__ w_hh,
                            const float* __restrict__ pit_w1,
                            const float* __restrict__ time_w1,
                            const float* __restrict__ ar_w1,
                            const float* __restrict__ ar_w2,
                            unsigned short* __restrict__ ws) {
  int idx = blockIdx.x * 256 + threadIdx.x;
  if (idx >= WS_TOTAL) return;
  int lane = (idx >> 3) & 63;
  int e    = idx & 7;
  int lrow = lane & 15, lgrp = lane >> 4;
  float v;
  if (idx < WS_PF) {
    int f = idx >> 9;                 // 0..639
    int w = f / 80, r = f - w * 80;
    int qm = r / 10, kt = r - qm * 10;
    int q = qm >> 1, m = qm & 1;
    int row = q * 256 + w * 32 + m * 16 + lrow;
    int col = kt * 32 + lgrp * 8 + e;
    v = (col < I_DIM) ? w_ih[row * I_DIM + col] : w_hh[row * 256 + col - I_DIM];
  } else if (idx < WS_TF) {
    int f = (idx - WS_PF) >> 9;       // 0..31
    int wv = f >> 3, kt = f & 7;
    v = pit_w1[(wv * 16 + lrow) * 256 + kt * 32 + lgrp * 8 + e];
  } else if (idx < WS_AXF) {
    int f = (idx - WS_TF) >> 9;
    int wv = f >> 3, kt = f & 7;
    v = time_w1[(wv * 16 + lrow) * 257 + kt * 32 + lgrp * 8 + e];
  } else if (idx < WS_A2F) {
    int f = (idx - WS_AXF) >> 9;      // 0..7
    int wv = f >> 1, kt = f & 1;
    v = ar_w1[(wv * 16 + lrow) * 66 + 2 + kt * 32 + lgrp * 8 + e];
  } else {
    int f = (idx - WS_A2F) >> 9;
    int wv = f >> 1, kt = f & 1;
    v = ar_w2[(wv * 16 + lrow) * 64 + kt * 32 + lgrp * 8 + e];
  }
  ws[idx] = f2bf(v);
}

#define AFRAG(kt) (*(const s16x8*)&A_lds[lrow][(kt) * 32 + 8 * lgrp])
#define GFRAG(kt, qm) \
  (*(const s16x8*)&ws[((wave * 8 + (qm)) * 10 + (kt)) * 512 + lane * 8])

// DMA chunk (kt, half) -> stg[wave][slot]: 4 frags (qm = half*4+j), 4KB.
#define DMA_CHUNK(kt, half, slot)                                              \
  do {                                                                         \
    _Pragma("unroll")                                                          \
    for (int j = 0; j < 4; ++j) {                                              \
      const unsigned short* gp =                                               \
          &ws[((wave * 8 + (half) * 4 + j) * 10 + (kt)) * 512 + lane * 8];     \
      gld16(gp, &stg[wave][slot][j * 512]);                                    \
    }                                                                          \
  } while (0)

// Consume chunk in slot: vmcnt(4) = this chunk ready, next still in flight.
// lgkmcnt(0) after MFMAs: slot's ds_reads executed -> safe to re-DMA the slot.
#define GCHUNK(af, half, slot)                                                 \
  do {                                                                         \
    asm volatile("s_waitcnt vmcnt(4)" ::: "memory");                           \
    _Pragma("unroll")                                                          \
    for (int j = 0; j < 4; ++j) {                                              \
      s16x8 b = *(const s16x8*)&stg[wave][slot][j * 512 + lane * 8];           \
      acc2[(half) * 4 + j] = __builtin_amdgcn_mfma_f32_16x16x32_bf16(          \
          (af), b, acc2[(half) * 4 + j], 0, 0, 0);                             \
    }                                                                          \
    asm volatile("s_waitcnt lgkmcnt(0)" ::: "memory");                         \
  } while (0)

__global__ __launch_bounds__(NT, 2) void rnn_kernel(
    const float* __restrict__ x,
    const float* __restrict__ b_ih, const float* __restrict__ b_hh,
    const float* __restrict__ pit_b1, const float* __restrict__ pit_w2,
    const float* __restrict__ pit_b2,
    const float* __restrict__ time_w1, const float* __restrict__ time_b1,
    const float* __restrict__ time_w2, const float* __restrict__ time_b2,
    const float* __restrict__ ar_w1, const float* __restrict__ ar_b1,
    const float* __restrict__ ar_b2,
    const unsigned short* __restrict__ ws,
    float* __restrict__ out)
{
  __shared__ __align__(16) unsigned short A_lds[16][ALD];    // [x(64) | h(256)]
  __shared__ __align__(16) unsigned short xo_lds[16][XLD];   // x_orig[t]
  __shared__ __align__(16) unsigned short ar1_lds[16][XLD];  // relu(ar1)
  __shared__ __align__(16) unsigned short pit_lds[32 * 512]; // pit_w1 (32 KB)
  __shared__ __align__(16) unsigned short tim_lds[32 * 512]; // time_w1 (32 KB)
  __shared__ __align__(16) unsigned short stg[8][2][2048];   // DMA ring (64 KB)
  __shared__ float pitp[4][16];
  __shared__ float timep[4][16];

  const int tid  = threadIdx.x;
  const int wave = tid >> 6;
  const int lane = tid & 63;
  const int lrow = lane & 15;
  const int lgrp = lane >> 4;
  const int b0   = blockIdx.x * 16;
  const int hcol = (wave & 3) * 16 + lrow;

  // ---- one-time LDS weight staging ----
  for (int c = tid; c < 2048; c += NT) {
    *(s16x8*)&pit_lds[c * 8] = *(const s16x8*)&ws[WS_PF + c * 8];
    *(s16x8*)&tim_lds[c * 8] = *(const s16x8*)&ws[WS_TF + c * 8];
  }
  for (int i = tid; i < 16 * ALD; i += NT) (&A_lds[0][0])[i] = 0;

  // ---- role constants ----
  float gbias[8];
#pragma unroll
  for (int qm = 0; qm < 8; ++qm) {
    int g = (qm >> 1) * 256 + wave * 32 + (qm & 1) * 16 + lrow;
    gbias[qm] = b_ih[g] + b_hh[g];
  }
  s16x8 arw[2];
  float pb1v = 0, pw2v = 0, tb1v = 0, tw2v = 0, twlv = 0;
  float ab1v = 0, arpv = 0, artv = 0, ab2v = 0;
  if (wave < 4) {
    arw[0] = *(const s16x8*)&ws[WS_AXF + ((wave & 3) * 2 + 0) * 512 + lane * 8];
    arw[1] = *(const s16x8*)&ws[WS_AXF + ((wave & 3) * 2 + 1) * 512 + lane * 8];
    pb1v = pit_b1[hcol]; pw2v = pit_w2[hcol];
    ab1v = ar_b1[hcol];  arpv = ar_w1[hcol * 66]; artv = ar_w1[hcol * 66 + 1];
  } else {
    arw[0] = *(const s16x8*)&ws[WS_A2F + ((wave & 3) * 2 + 0) * 512 + lane * 8];
    arw[1] = *(const s16x8*)&ws[WS_A2F + ((wave & 3) * 2 + 1) * 512 + lane * 8];
    tb1v = time_b1[hcol]; tw2v = time_w2[hcol];
    twlv = time_w1[hcol * 257 + 256]; ab2v = ar_b2[hcol];
  }
  const float pb2 = pit_b2[0], tb2 = time_b2[0];

  // ---- stage x[:,0,:], write ar_out[:,0,:] ----
  const int srow = tid >> 5;
  const int sc2  = (tid & 31) * 2;
  const size_t xbase = (size_t)(b0 + srow) * S_LEN * I_DIM + sc2;
  float2 xpre = *reinterpret_cast<const float2*>(&x[xbase]);
  __syncthreads();
  A_lds[srow][sc2]     = f2bf(xpre.x);
  A_lds[srow][sc2 + 1] = f2bf(xpre.y);
  *reinterpret_cast<float2*>(&out[OUT_AR + xbase]) = xpre;

  float cst[2][4];
#pragma unroll
  for (int m = 0; m < 2; ++m)
#pragma unroll
    for (int r = 0; r < 4; ++r) cst[m][r] = 0.0f;
  __syncthreads();

  // ---- prologue: gates(0) = bias + x0-part (h=0); direct register loads ----
  f32x4 acc2[8];
#pragma unroll
  for (int qm = 0; qm < 8; ++qm) {
    f32x4 tv; tv[0] = tv[1] = tv[2] = tv[3] = gbias[qm];
    acc2[qm] = tv;
  }
#pragma unroll
  for (int kt = 0; kt < 2; ++kt) {
    s16x8 aK = AFRAG(kt);
#pragma unroll
    for (int qm = 0; qm < 8; ++qm)
      acc2[qm] = __builtin_amdgcn_mfma_f32_16x16x32_bf16(aK, GFRAG(kt, qm), acc2[qm], 0, 0, 0);
  }
  // prime the ring: C0=(kt2,h0), C1=(kt2,h1)
  DMA_CHUNK(2, 0, 0);
  DMA_CHUNK(2, 1, 1);

  // =========================== time loop ===========================
  for (int t = 0; t < S_LEN; ++t) {
    // ---- P0: xo stage, x prefetch, LSTM -> h ----
    xo_lds[srow][sc2]     = f2bf(xpre.x);
    xo_lds[srow][sc2 + 1] = f2bf(xpre.y);
    if (t + 1 < S_LEN)
      xpre = *reinterpret_cast<const float2*>(&x[xbase + (size_t)(t + 1) * I_DIM]);

#pragma unroll
    for (int m = 0; m < 2; ++m)
#pragma unroll
      for (int r = 0; r < 4; ++r) {
        float ig = sigf(acc2[0 + m][r]);
        float fg = sigf(acc2[2 + m][r]);
        float gg = tanh_fast(acc2[4 + m][r]);
        float og = sigf(acc2[6 + m][r]);
        float c  = fg * cst[m][r] + ig * gg;
        cst[m][r] = c;
        A_lds[lgrp * 4 + r][64 + wave * 32 + m * 16 + lrow] = f2bf(og * tanh_fast(c));
      }
#pragma unroll
    for (int qm = 0; qm < 8; ++qm) {
      f32x4 tv; tv[0] = tv[1] = tv[2] = tv[3] = gbias[qm];
      acc2[qm] = tv;
    }
    sync_lds();  // barrier A: h + xo ready

    // ---- P1: heads main; pit reduce; gate chunks kt2..kt5 ----
    s16x8 hfr[8];
#pragma unroll
    for (int k = 0; k < 8; ++k)
      hfr[k] = *(const s16x8*)&A_lds[lrow][64 + k * 32 + 8 * lgrp];

    f32x4 hacc;
    {
      float hb = (wave < 4) ? pb1v : tb1v;
      hacc[0] = hacc[1] = hacc[2] = hacc[3] = hb;
      const unsigned short* hbp = (wave < 4) ? pit_lds : tim_lds;
#pragma unroll
      for (int kt = 0; kt < 8; ++kt) {
        s16x8 bH = *(const s16x8*)&hbp[(((wave & 3) * 8 + kt) * 64 + lane) * 8];
        hacc = __builtin_amdgcn_mfma_f32_16x16x32_bf16(hfr[kt], bH, hacc, 0, 0, 0);
      }
    }
    if (wave < 4) {  // pit partial reduce
      float v[4];
#pragma unroll
      for (int r = 0; r < 4; ++r) v[r] = fmaxf(hacc[r], 0.0f) * pw2v;
#pragma unroll
      for (int off = 1; off < 16; off <<= 1)
#pragma unroll
        for (int r = 0; r < 4; ++r) v[r] += __shfl_xor(v[r], off);
      if (lrow == 0) {
#pragma unroll
        for (int r = 0; r < 4; ++r) pitp[wave][lgrp * 4 + r] = v[r];
      }
    }
    GCHUNK(hfr[0], 0, 0); DMA_CHUNK(3, 0, 0);  // C0 kt2h0 -> issue C2
    GCHUNK(hfr[0], 1, 1); DMA_CHUNK(3, 1, 1);  // C1 -> C3
    GCHUNK(hfr[1], 0, 0); DMA_CHUNK(4, 0, 0);  // C2 kt3h0 -> C4
    GCHUNK(hfr[1], 1, 1); DMA_CHUNK(4, 1, 1);  // C3 -> C5
    GCHUNK(hfr[2], 0, 0); DMA_CHUNK(5, 0, 0);  // C4 kt4h0 -> C6
    GCHUNK(hfr[2], 1, 1); DMA_CHUNK(5, 1, 1);  // C5 -> C7
    GCHUNK(hfr[3], 0, 0); DMA_CHUNK(6, 0, 0);  // C6 kt5h0 -> C8
    GCHUNK(hfr[3], 1, 1); DMA_CHUNK(6, 1, 1);  // C7 -> C9
    sync_lds();  // barrier 1: pit partials ready

    // ---- P2: pv; time finish / ar1-x; pit out; chunks kt6,kt7 ----
    float pv[4];
#pragma unroll
    for (int r = 0; r < 4; ++r) {
      int row = lgrp * 4 + r;
      pv[r] = pitp[0][row] + pitp[1][row] + pitp[2][row] + pitp[3][row] + pb2;
    }
    f32x4 aracc;
    if (wave < 4) {
      aracc[0] = aracc[1] = aracc[2] = aracc[3] = ab1v;
#pragma unroll
      for (int kt = 0; kt < 2; ++kt) {
        s16x8 aX = *(const s16x8*)&xo_lds[lrow][kt * 32 + 8 * lgrp];
        aracc = __builtin_amdgcn_mfma_f32_16x16x32_bf16(aX, arw[kt], aracc, 0, 0, 0);
      }
      if (wave == 0 && lane < 16) {
        float pvs = pitp[0][lane] + pitp[1][lane] + pitp[2][lane] + pitp[3][lane] + pb2;
        out[OUT_PIT + (size_t)(b0 + lane) * S_LEN + t] = pvs;
      }
    } else {
      float v[4];
#pragma unroll
      for (int r = 0; r < 4; ++r)
        v[r] = fmaxf(hacc[r] + pv[r] * twlv, 0.0f) * tw2v;
#pragma unroll
      for (int off = 1; off < 16; off <<= 1)
#pragma unroll
        for (int r = 0; r < 4; ++r) v[r] += __shfl_xor(v[r], off);
      if (lrow == 0) {
#pragma unroll
        for (int r = 0; r < 4; ++r) timep[wave & 3][lgrp * 4 + r] = v[r];
      }
    }
    GCHUNK(hfr[4], 0, 0); DMA_CHUNK(7, 0, 0);  // C8 kt6h0 -> C10
    GCHUNK(hfr[4], 1, 1); DMA_CHUNK(7, 1, 1);  // C9 -> C11
    GCHUNK(hfr[5], 0, 0); DMA_CHUNK(8, 0, 0);  // C10 kt7h0 -> C12
    GCHUNK(hfr[5], 1, 1); DMA_CHUNK(8, 1, 1);  // C11 -> C13
    sync_lds();  // barrier 2: time partials ready

    // ---- P3: tv; ar1 finish; time out; chunks kt8,kt9 ----
    float tvv[4];
#pragma unroll
    for (int r = 0; r < 4; ++r) {
      int row = lgrp * 4 + r;
      tvv[r] = timep[0][row] + timep[1][row] + timep[2][row] + timep[3][row] + tb2;
    }
    if (wave < 4) {
#pragma unroll
      for (int r = 0; r < 4; ++r) {
        float a1 = aracc[r] + pv[r] * arpv + tvv[r] * artv;
        ar1_lds[lgrp * 4 + r][hcol] = f2bf(fmaxf(a1, 0.0f));
      }
    } else if (wave == 4 && lane < 16) {
      float tvs = timep[0][lane] + timep[1][lane] + timep[2][lane] + timep[3][lane] + tb2;
      out[OUT_TIME + (size_t)(b0 + lane) * S_LEN + t] = tvs;
    }
    GCHUNK(hfr[6], 0, 0); DMA_CHUNK(9, 0, 0);  // C12 kt8h0 -> C14
    GCHUNK(hfr[6], 1, 1); DMA_CHUNK(9, 1, 1);  // C13 -> C15
    GCHUNK(hfr[7], 0, 0); DMA_CHUNK(0, 0, 0);  // C14 kt9h0 -> C16 (kt0)
    GCHUNK(hfr[7], 1, 1); DMA_CHUNK(0, 1, 1);  // C15 -> C17
    sync_lds();  // barrier 3: ar1 ready

    // ---- P4: ar2 -> x_{t+1} (waves 4-7) ----
    if (wave >= 4) {
      f32x4 nacc;
      nacc[0] = nacc[1] = nacc[2] = nacc[3] = ab2v;
#pragma unroll
      for (int kt = 0; kt < 2; ++kt) {
        s16x8 aR = *(const s16x8*)&ar1_lds[lrow][kt * 32 + 8 * lgrp];
        nacc = __builtin_amdgcn_mfma_f32_16x16x32_bf16(aR, arw[kt], nacc, 0, 0, 0);
      }
#pragma unroll
      for (int r = 0; r < 4; ++r) {
        int row = lgrp * 4 + r;
        A_lds[row][hcol] = f2bf(nacc[r]);
        if (t < S_LEN - 1)
          out[OUT_AR + (size_t)(b0 + row) * S_LEN * I_DIM + (size_t)(t + 1) * I_DIM + hcol] = nacc[r];
      }
    }
    sync_lds();  // barrier B: x_{t+1} staged

    // ---- P5: gates-x chunks kt0,kt1; prime next step's kt2 ----
    {
      s16x8 a0 = AFRAG(0);
      GCHUNK(a0, 0, 0); DMA_CHUNK(1, 0, 0);    // C16 kt0h0 -> C18 (kt1h0)
      GCHUNK(a0, 1, 1); DMA_CHUNK(1, 1, 1);    // C17 -> C19
      s16x8 a1 = AFRAG(1);
      GCHUNK(a1, 0, 0); DMA_CHUNK(2, 0, 0);    // C18 kt1h0 -> C0' (next kt2)
      GCHUNK(a1, 1, 1); DMA_CHUNK(2, 1, 1);    // C19 -> C1'
    }
  }
}

extern "C" void kernel_launch(void* const* d_in, const int* in_sizes, int n_in,
                              void* d_out, int out_size, void* d_ws, size_t ws_size,
                              hipStream_t stream) {
  const float* x       = (const float*)d_in[0];
  const float* w_ih    = (const float*)d_in[1];
  const float* w_hh    = (const float*)d_in[2];
  const float* b_ih    = (const float*)d_in[3];
  const float* b_hh    = (const float*)d_in[4];
  const float* pit_w1  = (const float*)d_in[5];
  const float* pit_b1  = (const float*)d_in[6];
  const float* pit_w2  = (const float*)d_in[7];
  const float* pit_b2  = (const float*)d_in[8];
  const float* time_w1 = (const float*)d_in[9];
  const float* time_b1 = (const float*)d_in[10];
  const float* time_w2 = (const float*)d_in[11];
  const float* time_b2 = (const float*)d_in[12];
  const float* ar_w1   = (const float*)d_in[13];
  const float* ar_b1   = (const float*)d_in[14];
  const float* ar_w2   = (const float*)d_in[15];
  const float* ar_b2   = (const float*)d_in[16];
  unsigned short* ws   = (unsigned short*)d_ws;
  float* out           = (float*)d_out;

  prep_kernel<<<dim3((WS_TOTAL + 255) / 256), dim3(256), 0, stream>>>(
      w_ih, w_hh, pit_w1, time_w1, ar_w1, ar_w2, ws);
  rnn_kernel<<<dim3(16), dim3(NT), 0, stream>>>(
      x, b_ih, b_hh, pit_b1, pit_w2, pit_b2,
      time_w1, time_b1, time_w2, time_b2,
      ar_w1, ar_b1, ar_b2, ws, out);
}